// Round 12
// baseline (264.833 us; speedup 1.0000x reference)
//
#include <hip/hip_runtime.h>
#include <hip/hip_bf16.h>

#define IN_N    8192
#define OUT_N   8186
#define KS      7

#define SCOLS   512            // staged fp32 cols per strip (2 KB per row burst)
#define OCOLS   496            // output cols per strip
#define NSTRIP  17             // 16 full strips + 1 partial (cols 7936..8185)
#define NSEG    45             // vertical segments
#define NBLK    (NSTRIP * NSEG) // 765 blocks ~= 3/CU
#define NROWB   40             // circular buffer depth (rows)
#define LSTR    1040           // LDS bytes/row: 512*2 + 16 pad
#define NT8     31             // 16-col output tiles per strip
#define TOTSTEP 512            // 16-row steps covering all output rows

typedef __bf16 bf16x8 __attribute__((ext_vector_type(8)));
typedef float  f32x4  __attribute__((ext_vector_type(4)));
typedef float  f32x2  __attribute__((ext_vector_type(2)));

union BFU { __bf16 h; unsigned short u; };
__device__ __forceinline__ unsigned short f2bf(float f) {
    BFU c; c.h = (__bf16)f; return c.u;
}

template<bool G>
__device__ __forceinline__ void run_strip(
    const float* __restrict__ X, float* __restrict__ out,
    char* sb, const bf16x8* bfrag, float bv,
    int X0, int s0, int s1, int tid)
{
    const int lane = tid & 63;
    const int wv   = tid >> 6;
    const int lo   = lane & 15;
    const int hi   = lane >> 4;
    const int p    = tid >> 7;            // row parity for staging
    const int cg   = tid & 127;           // granule col 0..127
    const int ccol = X0 + 4 * cg;         // fp32 col of this thread's granule
    const int wcol = cg * 8;              // LDS byte col (4 bf16)

    // write-slot base for rows (16s + 22 + 2k + p); advanced by 16 mod 40 per step
    int wbase = (16 * s0 + 22 + p) % NROWB;

    // fragment read byte-offsets for rows (16s + lo + ky) mod 40
    int roff[KS];
    #pragma unroll
    for (int ky = 0; ky < KS; ++ky)
        roff[ky] = ((16 * s0 + lo + ky) % NROWB) * LSTR + 16 * hi;

    // ---- prologue: stage rows 16*s0 .. 16*s0+21 (11 rounds, 2816 granules) ----
    #pragma unroll
    for (int k = 0; k < 11; ++k) {
        int r = 16 * s0 + 2 * k + p;
        int c = ccol;
        if (G) { r = min(r, IN_N - 1); c = min(c, IN_N - 4); } // clamped junk only feeds guarded-out outputs
        float4 v = *(const float4*)(X + (size_t)r * IN_N + c);
        ushort4 h;
        h.x = f2bf(v.x); h.y = f2bf(v.y); h.z = f2bf(v.z); h.w = f2bf(v.w);
        const int slot = (16 * s0 + 2 * k + p) % NROWB;
        *(ushort4*)(sb + slot * LSTR + wcol) = h;
    }
    asm volatile("s_waitcnt lgkmcnt(0)" ::: "memory");
    __builtin_amdgcn_s_barrier();
    __builtin_amdgcn_sched_barrier(0);

    float4 ld[8];
    for (int s = s0; s < s1; ++s) {
        const int Y = 16 * s;
        const bool pre = (s + 1 < s1);

        // issue next 16 rows EARLY (1 KB contiguous per wave-load; latency hides under MFMA)
        if (pre) {
            #pragma unroll
            for (int k = 0; k < 8; ++k) {
                int r = Y + 22 + 2 * k + p;
                int c = ccol;
                if (G) { r = min(r, IN_N - 1); c = min(c, IN_N - 4); }
                ld[k] = *(const float4*)(X + (size_t)r * IN_N + c);
            }
        }
        __builtin_amdgcn_sched_barrier(0);

        // compute: tiles wv, wv+4, ... (31 tiles across 4 waves)
        for (int t8 = wv; t8 < NT8; t8 += 4) {
            const int off = 32 * t8;
            f32x4 accA = { bv, bv, bv, bv };
            f32x4 accB = { 0.f, 0.f, 0.f, 0.f };
            bf16x8 a0 = *(const bf16x8*)(sb + roff[0] + off);
            bf16x8 a1 = *(const bf16x8*)(sb + roff[1] + off);
            bf16x8 a2 = *(const bf16x8*)(sb + roff[2] + off);
            bf16x8 a3 = *(const bf16x8*)(sb + roff[3] + off);
            bf16x8 a4 = *(const bf16x8*)(sb + roff[4] + off);
            bf16x8 a5 = *(const bf16x8*)(sb + roff[5] + off);
            bf16x8 a6 = *(const bf16x8*)(sb + roff[6] + off);
            // swapped operands (A = Toeplitz^T); shared (lane,e)->k convention cancels HW k-permutation
            accA = __builtin_amdgcn_mfma_f32_16x16x32_bf16(bfrag[0], a0, accA, 0, 0, 0);
            accB = __builtin_amdgcn_mfma_f32_16x16x32_bf16(bfrag[1], a1, accB, 0, 0, 0);
            accA = __builtin_amdgcn_mfma_f32_16x16x32_bf16(bfrag[2], a2, accA, 0, 0, 0);
            accB = __builtin_amdgcn_mfma_f32_16x16x32_bf16(bfrag[3], a3, accB, 0, 0, 0);
            accA = __builtin_amdgcn_mfma_f32_16x16x32_bf16(bfrag[4], a4, accA, 0, 0, 0);
            accB = __builtin_amdgcn_mfma_f32_16x16x32_bf16(bfrag[5], a5, accB, 0, 0, 0);
            accA = __builtin_amdgcn_mfma_f32_16x16x32_bf16(bfrag[6], a6, accA, 0, 0, 0);
            const f32x4 acc = accA + accB;

            const int oy = Y + lo;                  // transposed D: lane lo = out row
            const int ox = X0 + 16 * t8 + 4 * hi;   // 4hi+reg = out col (even -> 8B aligned)
            if constexpr (!G) {
                f32x2* po = (f32x2*)(out + (size_t)oy * OUT_N + ox);
                const f32x2 v0 = { acc[0], acc[1] };
                const f32x2 v1 = { acc[2], acc[3] };
                __builtin_nontemporal_store(v0, po);      // nt: bypass L2/MALL allocate
                __builtin_nontemporal_store(v1, po + 1);
            } else {
                if (oy < OUT_N) {
                    #pragma unroll
                    for (int r = 0; r < 4; ++r)
                        if (ox + r < OUT_N)
                            __builtin_nontemporal_store(acc[r], &out[(size_t)oy * OUT_N + ox + r]);
                }
            }
        }
        __builtin_amdgcn_sched_barrier(0);

        // convert + ds_write rows Y+22..Y+37 (slots disjoint from this step's read slots mod 40)
        if (pre) {
            #pragma unroll
            for (int k = 0; k < 8; ++k) {
                ushort4 h;
                h.x = f2bf(ld[k].x); h.y = f2bf(ld[k].y);
                h.z = f2bf(ld[k].z); h.w = f2bf(ld[k].w);
                int slot = wbase + 2 * k;
                if (slot >= NROWB) slot -= NROWB;
                *(ushort4*)(sb + slot * LSTR + wcol) = h;
            }
            asm volatile("s_waitcnt lgkmcnt(0)" ::: "memory");  // writes visible
            __builtin_amdgcn_s_barrier();                        // one barrier per step
            __builtin_amdgcn_sched_barrier(0);
        }

        // advance circular indices
        wbase += 16; if (wbase >= NROWB) wbase -= NROWB;
        #pragma unroll
        for (int ky = 0; ky < KS; ++ky) {
            roff[ky] += 16 * LSTR;
            if (roff[ky] >= NROWB * LSTR) roff[ky] -= NROWB * LSTR;
        }
    }
}

__global__ __launch_bounds__(256, 3)
void conv7x7_nt(const float* __restrict__ X, const float* __restrict__ Kw,
                const float* __restrict__ bias, float* __restrict__ out) {
    __shared__ __align__(16) char sb[NROWB * LSTR];   // 41600 B -> 3 blocks/CU

    const int tid  = threadIdx.x;
    const int lane = tid & 63;
    const int lo   = lane & 15;
    const int hi   = lane >> 4;

    // bijective XCD swizzle for nwg=765 (q=95, r=5): contiguous wg band per XCD
    const int orig = blockIdx.x;
    const int xcd  = orig & 7;
    const int idx  = orig >> 3;
    const int wg   = (xcd < 5 ? xcd * 96 : 5 * 96 + (xcd - 5) * 95) + idx;
    const int seg   = wg / NSTRIP;     // seg-major: neighbors share the input row band
    const int strip = wg - seg * NSTRIP;

    const int X0 = strip * OCOLS;
    const int s0 = (TOTSTEP * seg) / NSEG;
    const int s1 = (TOTSTEP * (seg + 1)) / NSEG;

    // Toeplitz fragment: value w[ky][8*hi+e-lo] (identical expression for A- or B-slot)
    bf16x8 bfrag[KS];
    #pragma unroll
    for (int ky = 0; ky < KS; ++ky) {
        bf16x8 bv;
        #pragma unroll
        for (int e = 0; e < 8; ++e) {
            const int d = 8 * hi + e - lo;
            bv[e] = (__bf16)((d >= 0 && d < KS) ? Kw[ky * KS + d] : 0.0f);
        }
        bfrag[ky] = bv;
    }
    const float b = bias[0];

    if (strip < NSTRIP - 1 && seg < NSEG - 1)
        run_strip<false>(X, out, sb, bfrag, b, X0, s0, s1, tid);
    else
        run_strip<true >(X, out, sb, bfrag, b, X0, s0, s1, tid);
}

extern "C" void kernel_launch(void* const* d_in, const int* in_sizes, int n_in,
                              void* d_out, int out_size, void* d_ws, size_t ws_size,
                              hipStream_t stream) {
    const float* X    = (const float*)d_in[0];
    const float* Kw   = (const float*)d_in[1];
    const float* bias = (const float*)d_in[2];
    float* out = (float*)d_out;

    conv7x7_nt<<<dim3(NBLK), dim3(256), 0, stream>>>(X, Kw, bias, out);
}

// Round 13
// 158.998 us; speedup vs baseline: 1.6656x; 1.6656x over previous
//
#include <hip/hip_runtime.h>
#include <hip/hip_bf16.h>

#define IN_N    8192
#define OUT_N   8186
#define KS      7

#define SCOLS   320            // staged fp32 cols per strip
#define OCOLS   304            // output cols per strip
#define NSTRIP  27             // 26 full strips + 1 partial (cols 7904..8185)
#define NSEG    28
#define NBLK    (NSTRIP * NSEG) // 756 blocks ~= 3/CU
#define NROWB   38             // circular ring depth (22 read + 16 write rows)
#define LSTR    656            // ring bytes/row: 320*2 + 16 (/16 = 41 odd -> balanced b128)
#define OSTR    1232           // outbuf bytes/row: 304*4 + 16 (/16 = 77 odd)
#define NT8     19             // 16-col tiles per strip
#define NLD     5              // staging rounds/step: 16 rows * 80 granules / 256
#define TOTSTEP 512

typedef __bf16 bf16x8 __attribute__((ext_vector_type(8)));
typedef float  f32x4  __attribute__((ext_vector_type(4)));
typedef float  f32x2  __attribute__((ext_vector_type(2)));

union BFU { __bf16 h; unsigned short u; };
__device__ __forceinline__ unsigned short f2bf(float f) {
    BFU c; c.h = (__bf16)f; return c.u;
}

template<bool G>
__device__ __forceinline__ void run_strip(
    const float* __restrict__ X, float* __restrict__ out,
    char* ring, char* obuf, const bf16x8* bfrag, float bv,
    int X0, int s0, int s1, int tid)
{
    const int lane = tid & 63;
    const int wv   = tid >> 6;
    const int lo   = lane & 15;
    const int hi   = lane >> 4;

    // staging maps (step-invariant): granule g = k*256+tid over 16 rows x 80 granules
    int srow16[NLD], scol16[NLD], wslot[NLD];
    #pragma unroll
    for (int k = 0; k < NLD; ++k) {
        const int g = k * 256 + tid;
        srow16[k] = g / 80;
        scol16[k] = (g - srow16[k] * 80) * 4;
        wslot[k]  = (16 * s0 + 22 + srow16[k]) % NROWB;
    }
    int roff[KS];
    #pragma unroll
    for (int ky = 0; ky < KS; ++ky)
        roff[ky] = ((16 * s0 + lo + ky) % NROWB) * LSTR + 16 * hi;

    // ---- prologue: stage rows 16*s0 .. 16*s0+21 (22*80 = 1760 granules, 7 rounds) ----
    #pragma unroll
    for (int k = 0; k < 7; ++k) {
        const int g = k * 256 + tid;
        if (g < 1760) {
            const int pr = g / 80;
            const int pc = (g - pr * 80) * 4;
            int r = 16 * s0 + pr, c = X0 + pc;
            if (G) { r = min(r, IN_N - 1); c = min(c, IN_N - 4); } // junk only feeds guarded-out outputs
            float4 v = *(const float4*)(X + (size_t)r * IN_N + c);
            ushort4 h;
            h.x = f2bf(v.x); h.y = f2bf(v.y); h.z = f2bf(v.z); h.w = f2bf(v.w);
            *(ushort4*)(ring + ((16 * s0 + pr) % NROWB) * LSTR + pc * 2) = h;
        }
    }
    asm volatile("s_waitcnt lgkmcnt(0)" ::: "memory");
    __builtin_amdgcn_s_barrier();
    __builtin_amdgcn_sched_barrier(0);

    float4 ld[NLD];
    for (int s = s0; s < s1; ++s) {
        const int Y = 16 * s;
        const bool pre = (s + 1 < s1);

        // issue next 16 rows EARLY (1.25 KB contiguous per wave-load)
        if (pre) {
            #pragma unroll
            for (int k = 0; k < NLD; ++k) {
                int r = Y + 22 + srow16[k], c = X0 + scol16[k];
                if (G) { r = min(r, IN_N - 1); c = min(c, IN_N - 4); }
                ld[k] = *(const float4*)(X + (size_t)r * IN_N + c);
            }
        }
        __builtin_amdgcn_sched_barrier(0);

        // compute tiles wv, wv+4, ... (19 tiles over 4 waves); acc -> LDS outbuf
        for (int t8 = wv; t8 < NT8; t8 += 4) {
            const int off = 32 * t8;
            f32x4 accA = { bv, bv, bv, bv };
            f32x4 accB = { 0.f, 0.f, 0.f, 0.f };
            bf16x8 a0 = *(const bf16x8*)(ring + roff[0] + off);
            bf16x8 a1 = *(const bf16x8*)(ring + roff[1] + off);
            bf16x8 a2 = *(const bf16x8*)(ring + roff[2] + off);
            bf16x8 a3 = *(const bf16x8*)(ring + roff[3] + off);
            bf16x8 a4 = *(const bf16x8*)(ring + roff[4] + off);
            bf16x8 a5 = *(const bf16x8*)(ring + roff[5] + off);
            bf16x8 a6 = *(const bf16x8*)(ring + roff[6] + off);
            // swapped operands (A = Toeplitz^T); shared (lane,e)->k convention cancels HW k-permutation
            accA = __builtin_amdgcn_mfma_f32_16x16x32_bf16(bfrag[0], a0, accA, 0, 0, 0);
            accB = __builtin_amdgcn_mfma_f32_16x16x32_bf16(bfrag[1], a1, accB, 0, 0, 0);
            accA = __builtin_amdgcn_mfma_f32_16x16x32_bf16(bfrag[2], a2, accA, 0, 0, 0);
            accB = __builtin_amdgcn_mfma_f32_16x16x32_bf16(bfrag[3], a3, accB, 0, 0, 0);
            accA = __builtin_amdgcn_mfma_f32_16x16x32_bf16(bfrag[4], a4, accA, 0, 0, 0);
            accB = __builtin_amdgcn_mfma_f32_16x16x32_bf16(bfrag[5], a5, accB, 0, 0, 0);
            accA = __builtin_amdgcn_mfma_f32_16x16x32_bf16(bfrag[6], a6, accA, 0, 0, 0);
            const f32x4 acc = accA + accB;
            // transposed D: row = lo, cols 16*t8+4*hi..+3 ; 16B-aligned LDS write
            *(f32x4*)(obuf + lo * OSTR + (16 * t8 + 4 * hi) * 4) = acc;
        }
        asm volatile("s_waitcnt lgkmcnt(0)" ::: "memory");
        __builtin_amdgcn_s_barrier();
        __builtin_amdgcn_sched_barrier(0);

        // stream-out: wave-contiguous ~1.2 KB row bursts (76 float4 per row)
        #pragma unroll
        for (int j = 0; j < 4; ++j) {
            const int row = wv + 4 * j;
            const int oy  = Y + row;
            const size_t base = (size_t)oy * OUT_N + X0;
            if constexpr (!G) {
                {
                    const int f = lane;
                    f32x4 v = *(const f32x4*)(obuf + row * OSTR + f * 16);
                    const f32x2 v0 = { v[0], v[1] }, v1 = { v[2], v[3] };
                    *(f32x2*)(out + base + 4 * f)     = v0;   // 8B-aligned always
                    *(f32x2*)(out + base + 4 * f + 2) = v1;
                }
                if (lane < 12) {
                    const int f = lane + 64;
                    f32x4 v = *(const f32x4*)(obuf + row * OSTR + f * 16);
                    const f32x2 v0 = { v[0], v[1] }, v1 = { v[2], v[3] };
                    *(f32x2*)(out + base + 4 * f)     = v0;
                    *(f32x2*)(out + base + 4 * f + 2) = v1;
                }
            } else {
                if (oy < OUT_N) {
                    for (int f = lane; f < 76; f += 64) {
                        f32x4 v = *(const f32x4*)(obuf + row * OSTR + f * 16);
                        #pragma unroll
                        for (int e = 0; e < 4; ++e) {
                            const int c = X0 + 4 * f + e;
                            if (c < OUT_N) out[(size_t)oy * OUT_N + c] = v[e];
                        }
                    }
                }
            }
        }
        __builtin_amdgcn_sched_barrier(0);

        // convert + ring ds_write rows Y+22..Y+37 (slots disjoint from read slots mod 38)
        if (pre) {
            #pragma unroll
            for (int k = 0; k < NLD; ++k) {
                ushort4 h;
                h.x = f2bf(ld[k].x); h.y = f2bf(ld[k].y);
                h.z = f2bf(ld[k].z); h.w = f2bf(ld[k].w);
                *(ushort4*)(ring + wslot[k] * LSTR + scol16[k] * 2) = h;
            }
            asm volatile("s_waitcnt lgkmcnt(0)" ::: "memory");  // ring writes + obuf reads retired
            __builtin_amdgcn_s_barrier();                        // obuf safe to overwrite next step
            __builtin_amdgcn_sched_barrier(0);
        }

        // advance circular indices
        #pragma unroll
        for (int k = 0; k < NLD; ++k) {
            wslot[k] += 16; if (wslot[k] >= NROWB) wslot[k] -= NROWB;
        }
        #pragma unroll
        for (int ky = 0; ky < KS; ++ky) {
            roff[ky] += 16 * LSTR;
            if (roff[ky] >= NROWB * LSTR) roff[ky] -= NROWB * LSTR;
        }
    }
}

__global__ __launch_bounds__(256, 2)
void conv7x7_gather(const float* __restrict__ X, const float* __restrict__ Kw,
                    const float* __restrict__ bias, float* __restrict__ out) {
    __shared__ __align__(16) char ring[NROWB * LSTR];  // 24928 B
    __shared__ __align__(16) char obuf[16 * OSTR];     // 19712 B  (total 44640 -> 3 blocks/CU)

    const int tid  = threadIdx.x;
    const int lane = tid & 63;
    const int lo   = lane & 15;
    const int hi   = lane >> 4;

    // bijective XCD swizzle for nwg=756 (q=94, r=4)
    const int orig = blockIdx.x;
    const int xcd  = orig & 7;
    const int idx  = orig >> 3;
    const int wg   = (xcd < 4 ? xcd * 95 : 4 * 95 + (xcd - 4) * 94) + idx;
    const int seg   = wg / NSTRIP;     // seg-major: neighbors share the input row band
    const int strip = wg - seg * NSTRIP;

    const int X0 = strip * OCOLS;
    const int s0 = (TOTSTEP * seg) / NSEG;
    const int s1 = (TOTSTEP * (seg + 1)) / NSEG;

    // Toeplitz fragment: value w[ky][8*hi+e-lo] (identical expression for A- or B-slot)
    bf16x8 bfrag[KS];
    #pragma unroll
    for (int ky = 0; ky < KS; ++ky) {
        bf16x8 bv;
        #pragma unroll
        for (int e = 0; e < 8; ++e) {
            const int d = 8 * hi + e - lo;
            bv[e] = (__bf16)((d >= 0 && d < KS) ? Kw[ky * KS + d] : 0.0f);
        }
        bfrag[ky] = bv;
    }
    const float b = bias[0];

    if (strip < NSTRIP - 1 && seg < NSEG - 1)
        run_strip<false>(X, out, ring, obuf, bfrag, b, X0, s0, s1, tid);
    else
        run_strip<true >(X, out, ring, obuf, bfrag, b, X0, s0, s1, tid);
}

extern "C" void kernel_launch(void* const* d_in, const int* in_sizes, int n_in,
                              void* d_out, int out_size, void* d_ws, size_t ws_size,
                              hipStream_t stream) {
    const float* X    = (const float*)d_in[0];
    const float* Kw   = (const float*)d_in[1];
    const float* bias = (const float*)d_in[2];
    float* out = (float*)d_out;

    conv7x7_gather<<<dim3(NBLK), dim3(256), 0, stream>>>(X, Kw, bias, out);
}

// Round 14
// 141.058 us; speedup vs baseline: 1.8775x; 1.1272x over previous
//
#include <hip/hip_runtime.h>
#include <hip/hip_bf16.h>

#define IN_N    8192
#define OUT_N   8186
#define KS      7

#define SCOLS   512            // staged fp32 cols per strip (2 KB per row burst)
#define OCOLS   496            // output cols per strip
#define NSTRIP  17             // 16 full strips + 1 partial (cols 7936..8185)
#define NSEG    45             // vertical segments
#define NBLK    (NSTRIP * NSEG) // 765 blocks ~= 3/CU
#define NROWB   40             // circular buffer depth (rows)
#define LSTR    1040           // LDS bytes/row: 512*2 + 16 pad
#define NT8     31             // 16-col output tiles per strip
#define TOTSTEP 512            // 16-row steps covering all output rows

typedef __bf16 bf16x8 __attribute__((ext_vector_type(8)));
typedef float  f32x4  __attribute__((ext_vector_type(4)));

union BFU { __bf16 h; unsigned short u; };
__device__ __forceinline__ unsigned short f2bf(float f) {
    BFU c; c.h = (__bf16)f; return c.u;
}

template<bool G>
__device__ __forceinline__ void run_strip(
    const float* __restrict__ X, float* __restrict__ out,
    char* sb, const bf16x8* bfrag, float bv,
    int X0, int s0, int s1, int tid)
{
    const int lane = tid & 63;
    const int wv   = tid >> 6;
    const int lo   = lane & 15;
    const int hi   = lane >> 4;
    const int p    = tid >> 7;            // row parity for staging
    const int cg   = tid & 127;           // granule col 0..127
    const int ccol = X0 + 4 * cg;         // fp32 col of this thread's granule
    const int wcol = cg * 8;              // LDS byte col (4 bf16)

    // write-slot base for rows (16s + 22 + 2k + p); advanced by 16 mod 40 per step
    int wbase = (16 * s0 + 22 + p) % NROWB;

    // fragment read byte-offsets for rows (16s + lo + ky) mod 40
    int roff[KS];
    #pragma unroll
    for (int ky = 0; ky < KS; ++ky)
        roff[ky] = ((16 * s0 + lo + ky) % NROWB) * LSTR + 16 * hi;

    // ---- prologue: stage rows 16*s0 .. 16*s0+21 (11 rounds, 2816 granules) ----
    #pragma unroll
    for (int k = 0; k < 11; ++k) {
        int r = 16 * s0 + 2 * k + p;
        int c = ccol;
        if (G) { r = min(r, IN_N - 1); c = min(c, IN_N - 4); } // clamped junk only feeds guarded-out outputs
        float4 v = *(const float4*)(X + (size_t)r * IN_N + c);
        ushort4 h;
        h.x = f2bf(v.x); h.y = f2bf(v.y); h.z = f2bf(v.z); h.w = f2bf(v.w);
        const int slot = (16 * s0 + 2 * k + p) % NROWB;
        *(ushort4*)(sb + slot * LSTR + wcol) = h;
    }
    asm volatile("s_waitcnt lgkmcnt(0)" ::: "memory");
    __builtin_amdgcn_s_barrier();
    __builtin_amdgcn_sched_barrier(0);

    float4 ld[8];
    for (int s = s0; s < s1; ++s) {
        const int Y = 16 * s;
        const bool pre = (s + 1 < s1);

        // issue next 16 rows EARLY (1 KB contiguous per wave-load; latency hides under MFMA)
        if (pre) {
            #pragma unroll
            for (int k = 0; k < 8; ++k) {
                int r = Y + 22 + 2 * k + p;
                int c = ccol;
                if (G) { r = min(r, IN_N - 1); c = min(c, IN_N - 4); }
                ld[k] = *(const float4*)(X + (size_t)r * IN_N + c);
            }
        }
        __builtin_amdgcn_sched_barrier(0);

        // compute: tiles wv, wv+4, ... (31 tiles across 4 waves)
        for (int t8 = wv; t8 < NT8; t8 += 4) {
            const int off = 32 * t8;
            f32x4 accA = { bv, bv, bv, bv };
            f32x4 accB = { 0.f, 0.f, 0.f, 0.f };
            bf16x8 a0 = *(const bf16x8*)(sb + roff[0] + off);
            bf16x8 a1 = *(const bf16x8*)(sb + roff[1] + off);
            bf16x8 a2 = *(const bf16x8*)(sb + roff[2] + off);
            bf16x8 a3 = *(const bf16x8*)(sb + roff[3] + off);
            bf16x8 a4 = *(const bf16x8*)(sb + roff[4] + off);
            bf16x8 a5 = *(const bf16x8*)(sb + roff[5] + off);
            bf16x8 a6 = *(const bf16x8*)(sb + roff[6] + off);
            // swapped operands (A = Toeplitz^T); shared (lane,e)->k convention cancels HW k-permutation
            accA = __builtin_amdgcn_mfma_f32_16x16x32_bf16(bfrag[0], a0, accA, 0, 0, 0);
            accB = __builtin_amdgcn_mfma_f32_16x16x32_bf16(bfrag[1], a1, accB, 0, 0, 0);
            accA = __builtin_amdgcn_mfma_f32_16x16x32_bf16(bfrag[2], a2, accA, 0, 0, 0);
            accB = __builtin_amdgcn_mfma_f32_16x16x32_bf16(bfrag[3], a3, accB, 0, 0, 0);
            accA = __builtin_amdgcn_mfma_f32_16x16x32_bf16(bfrag[4], a4, accA, 0, 0, 0);
            accB = __builtin_amdgcn_mfma_f32_16x16x32_bf16(bfrag[5], a5, accB, 0, 0, 0);
            accA = __builtin_amdgcn_mfma_f32_16x16x32_bf16(bfrag[6], a6, accA, 0, 0, 0);
            const f32x4 acc = accA + accB;

            const int oy = Y + lo;                  // transposed D: lane lo = out row
            const int ox = X0 + 16 * t8 + 4 * hi;   // 4hi+reg = out col (even -> 8B aligned)
            if constexpr (!G) {
                float2* po = (float2*)(out + (size_t)oy * OUT_N + ox);
                po[0] = make_float2(acc[0], acc[1]);
                po[1] = make_float2(acc[2], acc[3]);
            } else {
                if (oy < OUT_N) {
                    #pragma unroll
                    for (int r = 0; r < 4; ++r)
                        if (ox + r < OUT_N) out[(size_t)oy * OUT_N + ox + r] = acc[r];
                }
            }
        }
        __builtin_amdgcn_sched_barrier(0);

        // convert + ds_write rows Y+22..Y+37 (slots disjoint from this step's read slots mod 40)
        if (pre) {
            #pragma unroll
            for (int k = 0; k < 8; ++k) {
                ushort4 h;
                h.x = f2bf(ld[k].x); h.y = f2bf(ld[k].y);
                h.z = f2bf(ld[k].z); h.w = f2bf(ld[k].w);
                int slot = wbase + 2 * k;
                if (slot >= NROWB) slot -= NROWB;
                *(ushort4*)(sb + slot * LSTR + wcol) = h;
            }
            asm volatile("s_waitcnt lgkmcnt(0)" ::: "memory");  // writes visible
            __builtin_amdgcn_s_barrier();                        // one barrier per step
            __builtin_amdgcn_sched_barrier(0);
        }

        // advance circular indices
        wbase += 16; if (wbase >= NROWB) wbase -= NROWB;
        #pragma unroll
        for (int ky = 0; ky < KS; ++ky) {
            roff[ky] += 16 * LSTR;
            if (roff[ky] >= NROWB * LSTR) roff[ky] -= NROWB * LSTR;
        }
    }
}

__global__ __launch_bounds__(256, 3)
void conv7x7_roll(const float* __restrict__ X, const float* __restrict__ Kw,
                  const float* __restrict__ bias, float* __restrict__ out) {
    __shared__ __align__(16) char sb[NROWB * LSTR];   // 41600 B -> 3 blocks/CU

    const int tid  = threadIdx.x;
    const int lane = tid & 63;
    const int lo   = lane & 15;
    const int hi   = lane >> 4;

    // bijective XCD swizzle for nwg=765 (q=95, r=5): contiguous wg band per XCD
    const int orig = blockIdx.x;
    const int xcd  = orig & 7;
    const int idx  = orig >> 3;
    const int wg   = (xcd < 5 ? xcd * 96 : 5 * 96 + (xcd - 5) * 95) + idx;
    const int seg   = wg / NSTRIP;     // seg-major: neighbors share the input row band
    const int strip = wg - seg * NSTRIP;

    const int X0 = strip * OCOLS;
    const int s0 = (TOTSTEP * seg) / NSEG;
    const int s1 = (TOTSTEP * (seg + 1)) / NSEG;

    // Toeplitz fragment: value w[ky][8*hi+e-lo] (identical expression for A- or B-slot)
    bf16x8 bfrag[KS];
    #pragma unroll
    for (int ky = 0; ky < KS; ++ky) {
        bf16x8 bv;
        #pragma unroll
        for (int e = 0; e < 8; ++e) {
            const int d = 8 * hi + e - lo;
            bv[e] = (__bf16)((d >= 0 && d < KS) ? Kw[ky * KS + d] : 0.0f);
        }
        bfrag[ky] = bv;
    }
    const float b = bias[0];

    if (strip < NSTRIP - 1 && seg < NSEG - 1)
        run_strip<false>(X, out, sb, bfrag, b, X0, s0, s1, tid);
    else
        run_strip<true >(X, out, sb, bfrag, b, X0, s0, s1, tid);
}

extern "C" void kernel_launch(void* const* d_in, const int* in_sizes, int n_in,
                              void* d_out, int out_size, void* d_ws, size_t ws_size,
                              hipStream_t stream) {
    const float* X    = (const float*)d_in[0];
    const float* Kw   = (const float*)d_in[1];
    const float* bias = (const float*)d_in[2];
    float* out = (float*)d_out;

    conv7x7_roll<<<dim3(NBLK), dim3(256), 0, stream>>>(X, Kw, bias, out);
}